// Round 1
// baseline (210.648 us; speedup 1.0000x reference)
//
#include <hip/hip_runtime.h>

// Graph2Col: stable stream compaction of (m=128, V=2048, R=32) int32 mapping.
// Valid (!= -1) entries first in row-major order; tail filled with -1.
// Output layout in d_out (int32): nodes_indices [total*2] then column_indices [total*3].
//
// R8: drop the LDS staging + copy_out entirely. Data is ~99.95% dense
//     (P(empty)=1/2049), so compacted ranks are sequential across each wave and
//     direct global record stores are already contiguous/coalesced:
//       nodes: one 8B int2 store per record (8B-aligned, perfectly coalesced)
//       cols:  three dword stores per 12B record; the three instructions jointly
//              fill every line of a contiguous 768B span per wave (L2 combines).
//     This removes R7's 16-way (stride-8) / 8-way (stride-12) LDS bank-conflicted
//     staging writes, the 8-way-conflicted copy_out reads, barrier 3, and 40KB of
//     LDS (occupancy 4 -> 8+ blocks/CU). Scan logic (verified) unchanged.

#define EMPTY_V (-1)

typedef int v2i __attribute__((ext_vector_type(2)));

constexpr int TOTAL = 8388608;                 // 128*2048*32
constexpr int BLOCK = 256;
constexpr int CHUNK = 2048;                    // elements per block
constexpr int NB = TOTAL / CHUNK;              // 4096 blocks
constexpr int SUBT = CHUNK / (BLOCK * 4);      // 2 sub-tiles of 1024 elements
constexpr int NWAVE = BLOCK / 64;              // 4 waves

// ---------------------------------------------------------------- count pass
__global__ __launch_bounds__(BLOCK) void k_count(const int* __restrict__ in,
                                                 int* __restrict__ counts) {
    const int b = blockIdx.x;
    const int tid = threadIdx.x;
    const int4* p = (const int4*)(in + (size_t)b * CHUNK);
    int c = 0;
#pragma unroll
    for (int s = 0; s < SUBT; ++s) {
        int4 v = p[s * BLOCK + tid];
        c += (v.x != EMPTY_V) + (v.y != EMPTY_V) + (v.z != EMPTY_V) + (v.w != EMPTY_V);
    }
    for (int d = 32; d; d >>= 1) c += __shfl_down(c, d, 64);
    __shared__ int ws[NWAVE];
    const int lane = tid & 63, wid = tid >> 6;
    if (lane == 0) ws[wid] = c;
    __syncthreads();
    if (tid == 0) counts[b] = ws[0] + ws[1] + ws[2] + ws[3];
}

// ---------------------- scatter: scan + direct coalesced record stores + tail
__global__ __launch_bounds__(BLOCK) void k_scatter(const int* __restrict__ in,
                                                   const int* __restrict__ counts,
                                                   int* __restrict__ out_nodes,
                                                   int* __restrict__ out_cols) {
    const int b = blockIdx.x;
    const int tid = threadIdx.x;
    const int lane = tid & 63, wid = tid >> 6;
    const unsigned long long below = lane ? ((~0ull) >> (64 - lane)) : 0ull;

    __shared__ int RED[NWAVE];          // scan partials
    __shared__ int WSUM[SUBT * NWAVE];  // per-subtile wave totals

    // ---- per-wave partials of the redundant exclusive scan over counts[NB]
    {
        int pa = 0;
        const int idx0 = tid * 16;
#pragma unroll
        for (int q = 0; q < 4; ++q) {
            const int4 c4 = ((const int4*)counts)[4 * tid + q];
            const int cs[4] = {c4.x, c4.y, c4.z, c4.w};
#pragma unroll
            for (int j = 0; j < 4; ++j)
                if (idx0 + 4 * q + j < b) pa += cs[j];
        }
        for (int d = 32; d; d >>= 1) pa += __shfl_down(pa, d, 64);
        if (lane == 0) RED[wid] = pa;
    }

    // ---- load chunk, ballots, publish per-wave totals
    int4 v[SUBT];
    int pre[SUBT];
    const int4* p = (const int4*)(in + (size_t)b * CHUNK);
#pragma unroll
    for (int s = 0; s < SUBT; ++s) {
        v[s] = p[s * BLOCK + tid];
        const unsigned long long b0 = __ballot(v[s].x != EMPTY_V);
        const unsigned long long b1 = __ballot(v[s].y != EMPTY_V);
        const unsigned long long b2 = __ballot(v[s].z != EMPTY_V);
        const unsigned long long b3 = __ballot(v[s].w != EMPTY_V);
        pre[s] = __popcll(b0 & below) + __popcll(b1 & below) +
                 __popcll(b2 & below) + __popcll(b3 & below);
        if (lane == 0)
            WSUM[s * NWAVE + wid] =
                __popcll(b0) + __popcll(b1) + __popcll(b2) + __popcll(b3);
    }
    __syncthreads();   // RED/WSUM visible

    // ---- block-exclusive global prefix + per-thread local ranks
    const int excl = RED[0] + RED[1] + RED[2] + RED[3];
    int myoff[SUBT];
    int acc = 0;
#pragma unroll
    for (int s = 0; s < SUBT; ++s) {
        int cs_ = 0, woff = 0;
#pragma unroll
        for (int w = 0; w < NWAVE; ++w) {
            const int x = WSUM[s * NWAVE + w];
            cs_ += x;
            if (w < wid) woff += x;
        }
        myoff[s] = excl + acc + woff + pre[s];   // global record rank
        acc += cs_;
    }
    const int blockValid = acc;

    // ---- direct record stores at compacted global ranks (dense across wave)
    const int row = b >> 5;        // 2048 elems/block, 65536 elems/output-row
#pragma unroll
    for (int s = 0; s < SUBT; ++s) {
        int g = myoff[s];
        const int rem0 = ((b & 31) << 11) + (s << 10) + (tid << 2);  // fi & 65535
        const int vals[4] = {v[s].x, v[s].y, v[s].z, v[s].w};
#pragma unroll
        for (int j = 0; j < 4; ++j) {
            if (vals[j] != EMPTY_V) {
                const int pp = rem0 + j;
                v2i nd = {row, vals[j]};
                *(v2i*)(out_nodes + 2 * (size_t)g) = nd;     // 8B-aligned int2
                int* cp = out_cols + 3 * (size_t)g;
                cp[0] = row;
                cp[1] = pp >> 5;    // vertex
                cp[2] = pp & 31;    // region
                ++g;
            }
        }
    }

    // ---- tail: this block's invalid entries, counted from the end.
    {
        const int inv_pref = b * CHUNK - excl;            // invalids before this block
        const int start = TOTAL - inv_pref - (CHUNK - blockValid);
        const int end = TOTAL - inv_pref;
        for (int pos = start + tid; pos < end; pos += BLOCK) {
            out_nodes[2 * pos]     = EMPTY_V;
            out_nodes[2 * pos + 1] = EMPTY_V;
            out_cols[3 * pos]      = EMPTY_V;
            out_cols[3 * pos + 1]  = EMPTY_V;
            out_cols[3 * pos + 2]  = EMPTY_V;
        }
    }
}

extern "C" void kernel_launch(void* const* d_in, const int* in_sizes, int n_in,
                              void* d_out, int out_size, void* d_ws, size_t ws_size,
                              hipStream_t stream) {
    const int* in = (const int*)d_in[0];
    int* out = (int*)d_out;
    int* out_nodes = out;                    // [TOTAL, 2] int32
    int* out_cols = out + 2 * (size_t)TOTAL; // [TOTAL, 3] int32
    int* counts = (int*)d_ws;                // [NB]

    k_count<<<NB, BLOCK, 0, stream>>>(in, counts);
    k_scatter<<<NB, BLOCK, 0, stream>>>(in, counts, out_nodes, out_cols);
}

// Round 2
// 196.598 us; speedup vs baseline: 1.0715x; 1.0715x over previous
//
#include <hip/hip_runtime.h>

// Graph2Col: stable stream compaction of (m=128, V=2048, R=32) int32 mapping.
// Valid (!= -1) entries first in row-major order; tail filled with -1.
// Output layout in d_out (int32): nodes_indices [total*2] then column_indices [total*3].
//
// R9: stage only the 2-dword payload (val, pp) per record via aligned ds_write_b64
//     (R7 staged the expanded 5-dword output at strides 8B/12B -> 16-way/8-way bank
//     conflicts on write AND read; R8's direct scatter paid 3x coalescer line-events
//     on the 12B-stride cols stores). Copy-out: record-level peel p makes excl+p
//     a multiple of 4, so each thread expands 4 records from four aligned
//     ds_read_b64 into 2 nodes-int4 + 3 cols-int4 -- minimal dense coalesced
//     stores, no per-dword div/mod, no misaligned scalar loops.
//     row = b>>5 is block-uniform; cols fields are pp>>5 / pp&31 (derived in regs).

#define EMPTY_V (-1)

typedef int v2i __attribute__((ext_vector_type(2)));
typedef int v4i __attribute__((ext_vector_type(4)));

constexpr int TOTAL = 8388608;                 // 128*2048*32
constexpr int BLOCK = 256;
constexpr int CHUNK = 2048;                    // elements per block
constexpr int NB = TOTAL / CHUNK;              // 4096 blocks
constexpr int SUBT = CHUNK / (BLOCK * 4);      // 2 sub-tiles of 1024 elements
constexpr int NWAVE = BLOCK / 64;              // 4 waves

// ---------------------------------------------------------------- count pass
__global__ __launch_bounds__(BLOCK) void k_count(const int* __restrict__ in,
                                                 int* __restrict__ counts) {
    const int b = blockIdx.x;
    const int tid = threadIdx.x;
    const int4* p = (const int4*)(in + (size_t)b * CHUNK);
    int c = 0;
#pragma unroll
    for (int s = 0; s < SUBT; ++s) {
        int4 v = p[s * BLOCK + tid];
        c += (v.x != EMPTY_V) + (v.y != EMPTY_V) + (v.z != EMPTY_V) + (v.w != EMPTY_V);
    }
    for (int d = 32; d; d >>= 1) c += __shfl_down(c, d, 64);
    __shared__ int ws[NWAVE];
    const int lane = tid & 63, wid = tid >> 6;
    if (lane == 0) ws[wid] = c;
    __syncthreads();
    if (tid == 0) counts[b] = ws[0] + ws[1] + ws[2] + ws[3];
}

// ---------------- scatter: scan + pair staging + register-expand copy-out
__global__ __launch_bounds__(BLOCK) void k_scatter(const int* __restrict__ in,
                                                   const int* __restrict__ counts,
                                                   int* __restrict__ out_nodes,
                                                   int* __restrict__ out_cols) {
    const int b = blockIdx.x;
    const int tid = threadIdx.x;
    const int lane = tid & 63, wid = tid >> 6;
    const unsigned long long below = lane ? ((~0ull) >> (64 - lane)) : 0ull;

    __shared__ int s_pair[2 * CHUNK];   // 16 KB: compacted (val, pp) pairs
    __shared__ int RED[NWAVE];          // scan partials
    __shared__ int WSUM[SUBT * NWAVE];  // per-subtile wave totals

    // ---- per-wave partials of the redundant exclusive scan over counts[NB]
    {
        int pa = 0;
        const int idx0 = tid * 16;
#pragma unroll
        for (int q = 0; q < 4; ++q) {
            const int4 c4 = ((const int4*)counts)[4 * tid + q];
            const int cs[4] = {c4.x, c4.y, c4.z, c4.w};
#pragma unroll
            for (int j = 0; j < 4; ++j)
                if (idx0 + 4 * q + j < b) pa += cs[j];
        }
        for (int d = 32; d; d >>= 1) pa += __shfl_down(pa, d, 64);
        if (lane == 0) RED[wid] = pa;
    }

    // ---- load chunk, ballots, publish per-wave totals
    int4 v[SUBT];
    int pre[SUBT];
    const int4* p = (const int4*)(in + (size_t)b * CHUNK);
#pragma unroll
    for (int s = 0; s < SUBT; ++s) {
        v[s] = p[s * BLOCK + tid];
        const unsigned long long b0 = __ballot(v[s].x != EMPTY_V);
        const unsigned long long b1 = __ballot(v[s].y != EMPTY_V);
        const unsigned long long b2 = __ballot(v[s].z != EMPTY_V);
        const unsigned long long b3 = __ballot(v[s].w != EMPTY_V);
        pre[s] = __popcll(b0 & below) + __popcll(b1 & below) +
                 __popcll(b2 & below) + __popcll(b3 & below);
        if (lane == 0)
            WSUM[s * NWAVE + wid] =
                __popcll(b0) + __popcll(b1) + __popcll(b2) + __popcll(b3);
    }
    __syncthreads();   // barrier 1: RED/WSUM visible

    // ---- block-exclusive global prefix + per-thread LOCAL ranks
    const int excl = RED[0] + RED[1] + RED[2] + RED[3];
    int myoff[SUBT];
    int acc = 0;
#pragma unroll
    for (int s = 0; s < SUBT; ++s) {
        int cs_ = 0, woff = 0;
#pragma unroll
        for (int w = 0; w < NWAVE; ++w) {
            const int x = WSUM[s * NWAVE + w];
            cs_ += x;
            if (w < wid) woff += x;
        }
        myoff[s] = acc + woff + pre[s];   // local record rank within block
        acc += cs_;
    }
    const int nv = acc;                   // blockValid

    // ---- stage compacted (val, pp) pairs: aligned ds_write_b64, no expansion
#pragma unroll
    for (int s = 0; s < SUBT; ++s) {
        int lp = myoff[s];
        const int rem0 = ((b & 31) << 11) + (s << 10) + (tid << 2);  // fi & 65535
        const int vals[4] = {v[s].x, v[s].y, v[s].z, v[s].w};
#pragma unroll
        for (int j = 0; j < 4; ++j) {
            if (vals[j] != EMPTY_V) {
                v2i t = {vals[j], rem0 + j};
                *(v2i*)&s_pair[2 * lp] = t;
                ++lp;
            }
        }
    }
    __syncthreads();   // barrier 2: staging complete

    // ---- copy-out: expand 4 records/thread into dense aligned int4 stores
    const int row = b >> 5;   // 65536 elems per output row, 2048 per block

    // record peel so excl+pl is a multiple of 4 -> both streams 16B-aligned
    int pl = (4 - (excl & 3)) & 3;
    if (pl > nv) pl = nv;
    if (tid < pl) {
        const int l = tid;
        const int val = s_pair[2 * l], pp = s_pair[2 * l + 1];
        const size_t g = (size_t)excl + l;
        out_nodes[2 * g] = row;  out_nodes[2 * g + 1] = val;
        out_cols[3 * g] = row;   out_cols[3 * g + 1] = pp >> 5;
        out_cols[3 * g + 2] = pp & 31;
    }

    const int nrec4 = (nv - pl) >> 2;     // body groups of 4 records
    for (int k = tid; k < nrec4; k += BLOCK) {
        const int l = pl + 4 * k;
        const v2i r0 = *(const v2i*)&s_pair[2 * l];
        const v2i r1 = *(const v2i*)&s_pair[2 * l + 2];
        const v2i r2 = *(const v2i*)&s_pair[2 * l + 4];
        const v2i r3 = *(const v2i*)&s_pair[2 * l + 6];
        const int h0 = r0.y >> 5, lo0 = r0.y & 31;
        const int h1 = r1.y >> 5, lo1 = r1.y & 31;
        const int h2 = r2.y >> 5, lo2 = r2.y & 31;
        const int h3 = r3.y >> 5, lo3 = r3.y & 31;
        const size_t g = (size_t)excl + l;          // g % 4 == 0
        v4i* np = (v4i*)(out_nodes + 2 * g);        // 32B-aligned
        v4i n0 = {row, r0.x, row, r1.x};
        v4i n1 = {row, r2.x, row, r3.x};
        np[0] = n0; np[1] = n1;
        v4i* cp = (v4i*)(out_cols + 3 * g);         // 16B-aligned (12*g % 16 == 0)
        v4i c0 = {row, h0, lo0, row};
        v4i c1 = {h1, lo1, row, h2};
        v4i c2 = {lo2, row, h3, lo3};
        cp[0] = c0; cp[1] = c1; cp[2] = c2;
    }

    // tail records (< 4)
    {
        const int lt = pl + 4 * nrec4;
        if (tid < nv - lt) {
            const int l = lt + tid;
            const int val = s_pair[2 * l], pp = s_pair[2 * l + 1];
            const size_t g = (size_t)excl + l;
            out_nodes[2 * g] = row;  out_nodes[2 * g + 1] = val;
            out_cols[3 * g] = row;   out_cols[3 * g + 1] = pp >> 5;
            out_cols[3 * g + 2] = pp & 31;
        }
    }

    // ---- tail: this block's invalid entries, counted from the end.
    {
        const int inv_pref = b * CHUNK - excl;            // invalids before this block
        const int start = TOTAL - inv_pref - (CHUNK - nv);
        const int end = TOTAL - inv_pref;
        for (int pos = start + tid; pos < end; pos += BLOCK) {
            out_nodes[2 * pos]     = EMPTY_V;
            out_nodes[2 * pos + 1] = EMPTY_V;
            out_cols[3 * pos]      = EMPTY_V;
            out_cols[3 * pos + 1]  = EMPTY_V;
            out_cols[3 * pos + 2]  = EMPTY_V;
        }
    }
}

extern "C" void kernel_launch(void* const* d_in, const int* in_sizes, int n_in,
                              void* d_out, int out_size, void* d_ws, size_t ws_size,
                              hipStream_t stream) {
    const int* in = (const int*)d_in[0];
    int* out = (int*)d_out;
    int* out_nodes = out;                    // [TOTAL, 2] int32
    int* out_cols = out + 2 * (size_t)TOTAL; // [TOTAL, 3] int32
    int* counts = (int*)d_ws;                // [NB]

    k_count<<<NB, BLOCK, 0, stream>>>(in, counts);
    k_scatter<<<NB, BLOCK, 0, stream>>>(in, counts, out_nodes, out_cols);
}

// Round 3
// 189.596 us; speedup vs baseline: 1.1110x; 1.0369x over previous
//
#include <hip/hip_runtime.h>

// Graph2Col: stable stream compaction of (m=128, V=2048, R=32) int32 mapping.
// Valid (!= -1) entries first in row-major order; tail filled with -1.
// Output layout in d_out (int32): nodes_indices [total*2] then column_indices [total*3].
//
// R10: R7's full-expansion LDS staging + dense copy-out (empirically the best
//      global-store pattern: lane-contiguous int4 stores = full-line transactions;
//      R8/R9's strided/scattered stores cost 2.6-4x L2 line-events) with R7's one
//      LDS flaw fixed: the first head=(4-(excl&3))&3 records are written DIRECTLY
//      to global (<=3 records/block), so the staged remainder starts at global
//      rank g0 % 4 == 0. Both streams are then 16B-aligned on LDS src AND global
//      dst simultaneously -> copy-out is pure ds_read_b128 -> global_store_dwordx4
//      (no misalignment peel, no scalar 8-way-conflicted ds_read_b32 loop).
//      LDS stays exactly 40KB -> 4 blocks/CU.

#define EMPTY_V (-1)

typedef int v2i __attribute__((ext_vector_type(2)));
typedef int v4i __attribute__((ext_vector_type(4)));

constexpr int TOTAL = 8388608;                 // 128*2048*32
constexpr int BLOCK = 256;
constexpr int CHUNK = 2048;                    // elements per block
constexpr int NB = TOTAL / CHUNK;              // 4096 blocks
constexpr int SUBT = CHUNK / (BLOCK * 4);      // 2 sub-tiles of 1024 elements
constexpr int NWAVE = BLOCK / 64;              // 4 waves

// ---------------------------------------------------------------- count pass
__global__ __launch_bounds__(BLOCK) void k_count(const int* __restrict__ in,
                                                 int* __restrict__ counts) {
    const int b = blockIdx.x;
    const int tid = threadIdx.x;
    const int4* p = (const int4*)(in + (size_t)b * CHUNK);
    int c = 0;
#pragma unroll
    for (int s = 0; s < SUBT; ++s) {
        int4 v = p[s * BLOCK + tid];
        c += (v.x != EMPTY_V) + (v.y != EMPTY_V) + (v.z != EMPTY_V) + (v.w != EMPTY_V);
    }
    for (int d = 32; d; d >>= 1) c += __shfl_down(c, d, 64);
    __shared__ int ws[NWAVE];
    const int lane = tid & 63, wid = tid >> 6;
    if (lane == 0) ws[wid] = c;
    __syncthreads();
    if (tid == 0) counts[b] = ws[0] + ws[1] + ws[2] + ws[3];
}

// ------- scatter: scan + head-aligned expanded staging + pure b128 copy-out
__global__ __launch_bounds__(BLOCK) void k_scatter(const int* __restrict__ in,
                                                   const int* __restrict__ counts,
                                                   int* __restrict__ out_nodes,
                                                   int* __restrict__ out_cols) {
    const int b = blockIdx.x;
    const int tid = threadIdx.x;
    const int lane = tid & 63, wid = tid >> 6;
    const unsigned long long below = lane ? ((~0ull) >> (64 - lane)) : 0ull;

    __shared__ int s_nodes[2 * CHUNK];   // 16 KB (head 48 B doubles as scan scratch)
    __shared__ int s_cols[3 * CHUNK];    // 24 KB
    int* RED = s_nodes;                  // [NWAVE]      scan partials
    int* WSUM = s_nodes + NWAVE;         // [SUBT*NWAVE] per-subtile wave totals

    // ---- per-wave partials of the redundant exclusive scan over counts[NB]
    {
        int pa = 0;
        const int idx0 = tid * 16;
#pragma unroll
        for (int q = 0; q < 4; ++q) {
            const int4 c4 = ((const int4*)counts)[4 * tid + q];
            const int cs[4] = {c4.x, c4.y, c4.z, c4.w};
#pragma unroll
            for (int j = 0; j < 4; ++j)
                if (idx0 + 4 * q + j < b) pa += cs[j];
        }
        for (int d = 32; d; d >>= 1) pa += __shfl_down(pa, d, 64);
        if (lane == 0) RED[wid] = pa;
    }

    // ---- load chunk, ballots, publish per-wave totals
    int4 v[SUBT];
    int pre[SUBT];
    const int4* p = (const int4*)(in + (size_t)b * CHUNK);
#pragma unroll
    for (int s = 0; s < SUBT; ++s) {
        v[s] = p[s * BLOCK + tid];
        const unsigned long long b0 = __ballot(v[s].x != EMPTY_V);
        const unsigned long long b1 = __ballot(v[s].y != EMPTY_V);
        const unsigned long long b2 = __ballot(v[s].z != EMPTY_V);
        const unsigned long long b3 = __ballot(v[s].w != EMPTY_V);
        pre[s] = __popcll(b0 & below) + __popcll(b1 & below) +
                 __popcll(b2 & below) + __popcll(b3 & below);
        if (lane == 0)
            WSUM[s * NWAVE + wid] =
                __popcll(b0) + __popcll(b1) + __popcll(b2) + __popcll(b3);
    }
    __syncthreads();   // barrier 1: RED/WSUM visible

    // ---- block-exclusive global prefix + per-thread LOCAL ranks
    const int excl = RED[0] + RED[1] + RED[2] + RED[3];
    int myoff[SUBT];
    int acc = 0;
#pragma unroll
    for (int s = 0; s < SUBT; ++s) {
        int cs_ = 0, woff = 0;
#pragma unroll
        for (int w = 0; w < NWAVE; ++w) {
            const int x = WSUM[s * NWAVE + w];
            cs_ += x;
            if (w < wid) woff += x;
        }
        myoff[s] = acc + woff + pre[s];   // local record rank within block
        acc += cs_;
    }
    const int nv = acc;                   // blockValid
    __syncthreads();   // barrier 2: scratch consumed, staging may overwrite

    // ---- head-aligned staging: first `head` records go straight to global,
    //      the rest are staged expanded at slot (rank - head).
    const int row = b >> 5;              // 65536 elems per output row
    int head = (4 - (excl & 3)) & 3;
    if (head > nv) head = nv;

#pragma unroll
    for (int s = 0; s < SUBT; ++s) {
        int lp = myoff[s];
        const int rem0 = ((b & 31) << 11) + (s << 10) + (tid << 2);  // fi & 65535
        const int vals[4] = {v[s].x, v[s].y, v[s].z, v[s].w};
#pragma unroll
        for (int j = 0; j < 4; ++j) {
            if (vals[j] != EMPTY_V) {
                const int pp = rem0 + j;
                if (lp < head) {                       // <=3 records per block
                    const size_t g = (size_t)excl + lp;
                    out_nodes[2 * g] = row;  out_nodes[2 * g + 1] = vals[j];
                    out_cols[3 * g] = row;   out_cols[3 * g + 1] = pp >> 5;
                    out_cols[3 * g + 2] = pp & 31;
                } else {
                    const int sl = lp - head;
                    v2i nd = {row, vals[j]};
                    *(v2i*)&s_nodes[2 * sl] = nd;      // aligned ds_write_b64
                    s_cols[3 * sl] = row;
                    s_cols[3 * sl + 1] = pp >> 5;
                    s_cols[3 * sl + 2] = pp & 31;
                }
                ++lp;
            }
        }
    }
    __syncthreads();   // barrier 3: staging complete

    // ---- copy-out: both src and dst 16B-aligned -> pure b128 stream
    const int nrec = nv - head;                  // staged records (>= 0)
    const size_t g0 = (size_t)excl + head;       // g0 % 4 == 0 when nrec > 0
    {
        const int ndw = 2 * nrec, q = ndw >> 2;  // nodes: tail is 0 or 2 dwords
        v4i* dst = (v4i*)(out_nodes + 2 * g0);
        const v4i* src = (const v4i*)s_nodes;
        for (int k = tid; k < q; k += BLOCK) dst[k] = src[k];
        if ((ndw & 3) && tid < (ndw & 3))
            out_nodes[2 * g0 + 4 * q + tid] = s_nodes[4 * q + tid];
    }
    {
        const int ndw = 3 * nrec, q = ndw >> 2;  // cols: tail is 0..3 dwords
        v4i* dst = (v4i*)(out_cols + 3 * g0);
        const v4i* src = (const v4i*)s_cols;
        for (int k = tid; k < q; k += BLOCK) dst[k] = src[k];
        if (tid < (ndw & 3))
            out_cols[3 * g0 + 4 * q + tid] = s_cols[4 * q + tid];
    }

    // ---- tail: this block's invalid entries, counted from the end.
    {
        const int inv_pref = b * CHUNK - excl;            // invalids before this block
        const int start = TOTAL - inv_pref - (CHUNK - nv);
        const int end = TOTAL - inv_pref;
        for (int pos = start + tid; pos < end; pos += BLOCK) {
            out_nodes[2 * pos]     = EMPTY_V;
            out_nodes[2 * pos + 1] = EMPTY_V;
            out_cols[3 * pos]      = EMPTY_V;
            out_cols[3 * pos + 1]  = EMPTY_V;
            out_cols[3 * pos + 2]  = EMPTY_V;
        }
    }
}

extern "C" void kernel_launch(void* const* d_in, const int* in_sizes, int n_in,
                              void* d_out, int out_size, void* d_ws, size_t ws_size,
                              hipStream_t stream) {
    const int* in = (const int*)d_in[0];
    int* out = (int*)d_out;
    int* out_nodes = out;                    // [TOTAL, 2] int32
    int* out_cols = out + 2 * (size_t)TOTAL; // [TOTAL, 3] int32
    int* counts = (int*)d_ws;                // [NB]

    k_count<<<NB, BLOCK, 0, stream>>>(in, counts);
    k_scatter<<<NB, BLOCK, 0, stream>>>(in, counts, out_nodes, out_cols);
}